// Round 2
// baseline (138.047 us; speedup 1.0000x reference)
//
#include <hip/hip_runtime.h>

// CostVolume: x,y fp32 [2,64,96,320]; GROUP=8 -> 16 (b,g) slabs x 8 channels.
// cost[bg,d,h,j] = sum_cc | xn[cc,j] - (j>=d ? yn[cc,j-d] : 0) |,
// xn/yn = per-pixel channel L2-normalized (norm + 1e-5).
// Output [2,8,49,96,320] fp32.
//
// One block per (bg,h) row, 320 threads.
// Phase A: thread t normalizes column t, stages xn/yn channel-major in LDS.
// Phase B: thread (q=t%80, dc=t/80) owns column quad Q=4q and a chunk of
// disparity groups g (d=4g..4g+3). Per (g,channel) the needed y window is the
// two ALIGNED quads (q-g-1, q-g) -> 2 conflict-free ds_read_b128; 16 outputs
// per group at 16 B/output LDS traffic. Stores are float4 (16 B/lane).
// Left-pad boundary (j<d) -> cost = sum|xn| via branchless select.

#define HH   96
#define WW   320
#define HW   (HH * WW)      // 30720
#define NDISP 49
#define EPSN 1e-5f

__global__ __launch_bounds__(WW) void cost_volume_kernel(
    const float* __restrict__ x, const float* __restrict__ y,
    float* __restrict__ out)
{
    __shared__ float xn_s[8][WW];
    __shared__ float yn_s[8][WW];

    const int t   = threadIdx.x;     // 0..319
    const int blk = blockIdx.x;      // 0..1535
    const int h   = blk % HH;
    const int bg  = blk / HH;        // 0..15

    const size_t inBase = (size_t)bg * 8 * HW + (size_t)h * WW;

    // ---- Phase A: normalize column t, stage to LDS (channel-major) ----
    {
        float xv[8], yv[8];
        float xs = 0.f, ys = 0.f;
#pragma unroll
        for (int cc = 0; cc < 8; ++cc) {
            float xi = x[inBase + (size_t)cc * HW + t];
            float yi = y[inBase + (size_t)cc * HW + t];
            xv[cc] = xi; yv[cc] = yi;
            xs += xi * xi;
            ys += yi * yi;
        }
        const float xinv = 1.f / (sqrtf(xs) + EPSN);
        const float yinv = 1.f / (sqrtf(ys) + EPSN);
#pragma unroll
        for (int cc = 0; cc < 8; ++cc) {
            xn_s[cc][t] = xv[cc] * xinv;
            yn_s[cc][t] = yv[cc] * yinv;
        }
    }
    __syncthreads();

    // ---- Phase B: quad q, disparity-chunk dc ----
    const int q  = t % 80;
    const int dc = t / 80;          // 0..3
    const int Q  = q * 4;

    // xn quad in registers (aligned conflict-free b128 reads)
    float4 xq[8];
#pragma unroll
    for (int cc = 0; cc < 8; ++cc)
        xq[cc] = *(const float4*)&xn_s[cc][Q];

    // boundary cost per column: sum_cc |xn|
    float4 sA = make_float4(0.f, 0.f, 0.f, 0.f);
#pragma unroll
    for (int cc = 0; cc < 8; ++cc) {
        sA.x += fabsf(xq[cc].x);
        sA.y += fabsf(xq[cc].y);
        sA.z += fabsf(xq[cc].z);
        sA.w += fabsf(xq[cc].w);
    }

    // disparity-group chunks: dc0 -> g 0..3, dc1 -> 4..6, dc2 -> 7..9, dc3 -> 10..12
    const int g0 = (dc == 0) ? 0 : (3 * dc + 1);
    const int g1 = 3 * dc + 4;

    float* outp = out + (size_t)bg * (NDISP * HW) + (size_t)h * WW + Q;

    for (int g = g0; g < g1; ++g) {
        // y window: columns [Q-4(g+1) .. Q+3-4g] = aligned quads (q-g-1, q-g)
        int wq0 = q - g - 1; if (wq0 < 0) wq0 = 0;   // clamped reads only feed
        int wq1 = q - g;     if (wq1 < 0) wq1 = 0;   // boundary-overridden lanes
        const int a0 = wq0 * 4, a1 = wq1 * 4;

        float acc[4][4];   // [e][k]
#pragma unroll
        for (int e = 0; e < 4; ++e)
#pragma unroll
            for (int k = 0; k < 4; ++k) acc[e][k] = 0.f;

#pragma unroll
        for (int cc = 0; cc < 8; ++cc) {
            const float4 wa = *(const float4*)&yn_s[cc][a0];
            const float4 wb = *(const float4*)&yn_s[cc][a1];
            const float win[8] = { wa.x, wa.y, wa.z, wa.w,
                                   wb.x, wb.y, wb.z, wb.w };
            const float4 xc = xq[cc];
#pragma unroll
            for (int e = 0; e < 4; ++e) {
                // column k at disparity d=4g+e needs win[k+4-e]
                acc[e][0] += fabsf(xc.x - win[4 - e]);
                acc[e][1] += fabsf(xc.y - win[5 - e]);
                acc[e][2] += fabsf(xc.z - win[6 - e]);
                acc[e][3] += fabsf(xc.w - win[7 - e]);
            }
        }

#pragma unroll
        for (int e = 0; e < 4; ++e) {
            const int d = 4 * g + e;
            float4 r;
            r.x = (Q + 0 < d) ? sA.x : acc[e][0];
            r.y = (Q + 1 < d) ? sA.y : acc[e][1];
            r.z = (Q + 2 < d) ? sA.z : acc[e][2];
            r.w = (Q + 3 < d) ? sA.w : acc[e][3];
            if (d < NDISP)
                *(float4*)&outp[(size_t)d * HW] = r;
        }
    }
}

extern "C" void kernel_launch(void* const* d_in, const int* in_sizes, int n_in,
                              void* d_out, int out_size, void* d_ws, size_t ws_size,
                              hipStream_t stream) {
    const float* x = (const float*)d_in[0];
    const float* y = (const float*)d_in[1];
    float* out = (float*)d_out;
    dim3 grid(2 * 8 * HH);   // 1536 blocks: one per (b,g,h) row
    dim3 block(WW);          // 320 threads = 5 waves
    cost_volume_kernel<<<grid, block, 0, stream>>>(x, y, out);
}